// Round 1
// baseline (4559.592 us; speedup 1.0000x reference)
//
#include <hip/hip_runtime.h>
#include <math.h>

#define Bdim 8
#define Cdim 64
#define Ndim 4096

// ---------------------------------------------------------------------------
// Kernel 1: QKV projection.
// qkv[b,n,j] = sum_c x[b,c,n] * w_qkv[j,c]  (j in [0,192))
// Output layout: channel-major Q/K/V[b][c][n] so later tile loads & final
// stores are lane-coalesced over n.
// grid = B * (N/64) * 3 blocks of 64 threads; each block: one batch, 64 n,
// one 64-row j-chunk (0=Q,1=K,2=V).
// ---------------------------------------------------------------------------
__global__ __launch_bounds__(64) void qkv_kernel(
    const float* __restrict__ x, const float* __restrict__ w_qkv,
    float* __restrict__ Q, float* __restrict__ K, float* __restrict__ V)
{
    __shared__ float ws[64 * 64];
    const int bx  = blockIdx.x;
    const int jc  = bx % 3;
    const int nc  = (bx / 3) % (Ndim / 64);
    const int b   = bx / (3 * (Ndim / 64));
    const int tid = threadIdx.x;
    const int n   = nc * 64 + tid;

    for (int i = tid; i < 64 * 64; i += 64) ws[i] = w_qkv[jc * 64 * 64 + i];

    float xr[64];
#pragma unroll
    for (int c = 0; c < 64; ++c)
        xr[c] = x[((size_t)(b * 64 + c)) * Ndim + n];
    __syncthreads();

    float* outbase = (jc == 0) ? Q : (jc == 1) ? K : V;
    for (int j = 0; j < 64; ++j) {
        float acc = 0.f;
#pragma unroll
        for (int c = 0; c < 64; ++c) acc += xr[c] * ws[j * 64 + c];
        outbase[((size_t)(b * 64 + j)) * Ndim + n] = acc;
    }
}

// ---------------------------------------------------------------------------
// Kernel 2: fused flash attention + output projection.
// One thread owns one q-row (n). K/V staged per 64-key tile in LDS as
// [c][m] (conflict-free stride-1 writes; uniform broadcast b128 reads).
// Online softmax in chunks of 16 keys. Epilogue applies w_proj (in LDS)
// + b_proj and stores channel-major output.
// grid = B * (N/64) blocks of 64 threads.
// ---------------------------------------------------------------------------
__global__ __launch_bounds__(64) void attn_kernel(
    const float* __restrict__ Q, const float* __restrict__ K,
    const float* __restrict__ V, const int* __restrict__ fg,
    const float* __restrict__ w_proj, const float* __restrict__ b_proj,
    float* __restrict__ out)
{
    __shared__ float kt[64 * 64];   // kt[c][m]
    __shared__ float vt[64 * 64];   // vt[c][m]
    __shared__ float wp[64 * 64];   // w_proj[co][c]
    __shared__ float mt[64];        // mask tile (0/1)

    const int bx  = blockIdx.x;
    const int b   = bx >> 6;
    const int tid = threadIdx.x;
    const int n   = (bx & 63) * 64 + tid;

    for (int i = tid; i < 64 * 64; i += 64) wp[i] = w_proj[i];

    float q[64];
#pragma unroll
    for (int c = 0; c < 64; ++c)
        q[c] = Q[((size_t)(b * 64 + c)) * Ndim + n];

    float acc[64];
#pragma unroll
    for (int c = 0; c < 64; ++c) acc[c] = 0.f;
    float m_run = -1e30f, l_run = 0.f;

    for (int t = 0; t < Ndim / 64; ++t) {
        const int m0 = t * 64;
        __syncthreads();
#pragma unroll
        for (int c = 0; c < 64; ++c) {
            kt[c * 64 + tid] = K[((size_t)(b * 64 + c)) * Ndim + m0 + tid];
            vt[c * 64 + tid] = V[((size_t)(b * 64 + c)) * Ndim + m0 + tid];
        }
        mt[tid] = (fg[b * Ndim + m0 + tid] != 0) ? 1.f : 0.f;
        __syncthreads();

        for (int ch = 0; ch < 4; ++ch) {
            const int j0 = ch * 16;
            float s[16];
#pragma unroll
            for (int jj = 0; jj < 16; ++jj) s[jj] = 0.f;
#pragma unroll
            for (int c = 0; c < 64; ++c) {
                const float qc = q[c];
#pragma unroll
                for (int jj = 0; jj < 16; ++jj)
                    s[jj] += qc * kt[c * 64 + j0 + jj];
            }
            // mask + scale, chunk max
            float cmax = -1e30f;
#pragma unroll
            for (int jj = 0; jj < 16; ++jj) {
                const float mk = mt[j0 + jj];
                const float sv = (mk != 0.f) ? s[jj] * 0.125f : -1e30f;
                s[jj] = sv;
                cmax  = fmaxf(cmax, sv);
            }
            const float m_new = fmaxf(m_run, cmax);
            const float scale = __expf(m_run - m_new);
            float psum = 0.f;
#pragma unroll
            for (int jj = 0; jj < 16; ++jj) {
                const float mk = mt[j0 + jj];
                const float pv = mk * __expf(s[jj] - m_new);
                s[jj] = pv;            // s now holds p
                psum += pv;
            }
            l_run = l_run * scale + psum;
            m_run = m_new;
#pragma unroll
            for (int c = 0; c < 64; ++c) {
                float a = acc[c] * scale;
#pragma unroll
                for (int jj = 0; jj < 16; ++jj)
                    a += s[jj] * vt[c * 64 + j0 + jj];
                acc[c] = a;
            }
        }
    }

    const float inv_l = 1.f / l_run;
#pragma unroll
    for (int c = 0; c < 64; ++c) acc[c] *= inv_l;

    // fused out-projection: y[co] = b_proj[co] + sum_c acc[c] * w_proj[co][c]
    for (int co = 0; co < 64; ++co) {
        float y = b_proj[co];
#pragma unroll
        for (int c = 0; c < 64; ++c) y += acc[c] * wp[co * 64 + c];
        out[((size_t)(b * 64 + co)) * Ndim + n] = y;
    }
}

extern "C" void kernel_launch(void* const* d_in, const int* in_sizes, int n_in,
                              void* d_out, int out_size, void* d_ws, size_t ws_size,
                              hipStream_t stream) {
    const float* x      = (const float*)d_in[0];
    const int*   fg     = (const int*)d_in[1];
    const float* w_qkv  = (const float*)d_in[2];
    const float* w_proj = (const float*)d_in[3];
    const float* b_proj = (const float*)d_in[4];
    float* out = (float*)d_out;

    float* ws = (float*)d_ws;
    const size_t per = (size_t)Bdim * Cdim * Ndim;  // 2,097,152 floats
    float* Q = ws;
    float* K = ws + per;
    float* V = ws + 2 * per;

    qkv_kernel<<<dim3(Bdim * (Ndim / 64) * 3), dim3(64), 0, stream>>>(
        x, w_qkv, Q, K, V);
    attn_kernel<<<dim3(Bdim * (Ndim / 64)), dim3(64), 0, stream>>>(
        Q, K, V, fg, w_proj, b_proj, out);
}

// Round 2
// 215.338 us; speedup vs baseline: 21.1741x; 21.1741x over previous
//
#include <hip/hip_runtime.h>
#include <math.h>

#define Bdim 8
#define Cdim 64
#define Ndim 4096

typedef __bf16 bf16x8 __attribute__((ext_vector_type(8)));
typedef float  f32x4  __attribute__((ext_vector_type(4)));

// ---------------------------------------------------------------------------
// Kernel 1: QKV projection (fp32 compute, bf16 outputs).
// Layouts chosen for the MFMA attention kernel:
//   Qb [B][N][C] row-major  (A-fragment loads: 16B contiguous per lane)
//   Kb [B][N][C] row-major  (LDS staging: row copy)
//   Vb [B][C][N] chan-major (LDS staging of V^T: row copy)
// ---------------------------------------------------------------------------
__global__ __launch_bounds__(64) void qkv_kernel(
    const float* __restrict__ x, const float* __restrict__ w_qkv,
    __bf16* __restrict__ Qb, __bf16* __restrict__ Kb, __bf16* __restrict__ Vb)
{
    __shared__ float wsm[64 * 64];
    const int bx  = blockIdx.x;
    const int jc  = bx % 3;
    const int nc  = (bx / 3) % (Ndim / 64);
    const int b   = bx / (3 * (Ndim / 64));
    const int tid = threadIdx.x;
    const int n   = nc * 64 + tid;

    for (int i = tid; i < 64 * 64; i += 64) wsm[i] = w_qkv[jc * 64 * 64 + i];

    float xr[64];
#pragma unroll
    for (int c = 0; c < 64; ++c)
        xr[c] = x[((size_t)(b * 64 + c)) * Ndim + n];
    __syncthreads();

    float acc[64];
    for (int j = 0; j < 64; ++j) {
        float a = 0.f;
#pragma unroll
        for (int c = 0; c < 64; ++c) a += xr[c] * wsm[j * 64 + c];
        acc[j] = a;
    }

    if (jc == 2) {
        // V: channel-major, coalesced 2B stores
#pragma unroll
        for (int j = 0; j < 64; ++j)
            Vb[((size_t)(b * 64 + j)) * Ndim + n] = (__bf16)acc[j];
    } else {
        __bf16 row[64];
#pragma unroll
        for (int j = 0; j < 64; ++j) row[j] = (__bf16)acc[j];
        __bf16* dst = ((jc == 0) ? Qb : Kb) + ((size_t)(b * Ndim) + n) * 64;
        const uint4* src = (const uint4*)row;
#pragma unroll
        for (int i = 0; i < 8; ++i) ((uint4*)dst)[i] = src[i];
    }
}

// ---------------------------------------------------------------------------
// Kernel 2: MFMA flash attention + fused out-projection.
// Block = 4 waves (256 thr), 64 q-rows (16/wave). KV tiles of 64 keys.
// mfma_f32_16x16x32_bf16 layouts (m89-verified):
//   A: lane holds A[row=l&15][k=8*(l>>4)+j]   (8 bf16 = 16B contiguous)
//   B: lane holds B[k=8*(l>>4)+j][col=l&15]
//   D: lane holds D[row=(l>>4)*4+r][col=l&15] (f32x4)
// LDS XOR swizzle elem ^= (row&7)*8 kills the 128B-row-stride bank conflict.
// ---------------------------------------------------------------------------
__global__ __launch_bounds__(256) void attn_kernel(
    const __bf16* __restrict__ Qb, const __bf16* __restrict__ Kb,
    const __bf16* __restrict__ Vb, const int* __restrict__ fg,
    const float* __restrict__ w_proj, const float* __restrict__ b_proj,
    float* __restrict__ out)
{
    __shared__ __bf16 kt[64 * 64];      // kt[key][c]  swizzled
    __shared__ __bf16 vt[64 * 64];      // vt[c][key]  swizzled (V^T)
    __shared__ __bf16 pt[4 * 16 * 64];  // per-wave P/O bounce [16][64] swizzled
    __shared__ float  mt[64];

    const int bx   = blockIdx.x;
    const int b    = bx >> 6;
    const int qblk = bx & 63;
    const int tid  = threadIdx.x;
    const int wv   = tid >> 6;
    const int l    = tid & 63;
    const int g    = l >> 4;
    const int li   = l & 15;

    // Q A-fragments (held all kernel): rows qblk*64 + wv*16 + li
    const int qrow = qblk * 64 + wv * 16 + li;
    const __bf16* qbase = Qb + (((size_t)b * Ndim + qrow) * 64);
    const bf16x8 qa0 = *(const bf16x8*)(qbase + 8 * g);
    const bf16x8 qa1 = *(const bf16x8*)(qbase + 32 + 8 * g);

    f32x4 accv[4];
#pragma unroll
    for (int ct = 0; ct < 4; ++ct) accv[ct] = (f32x4){0.f, 0.f, 0.f, 0.f};
    float mrun[4] = {-1e30f, -1e30f, -1e30f, -1e30f};
    float lrun[4] = {0.f, 0.f, 0.f, 0.f};

    __bf16* ptw = pt + wv * 1024;

    for (int t = 0; t < Ndim / 64; ++t) {
        const int k0 = t * 64;
        __syncthreads();
        // ---- stage K-tile (row-major [key][c], swizzled) ----
#pragma unroll
        for (int ch = tid; ch < 512; ch += 256) {
            const int key = ch >> 3, cc = (ch & 7) * 8;
            uint4 d = *(const uint4*)(Kb + (((size_t)b * Ndim + k0 + key) * 64 + cc));
            *(uint4*)(kt + key * 64 + (cc ^ ((key & 7) * 8))) = d;
        }
        // ---- stage V^T-tile ([c][key], swizzled) ----
#pragma unroll
        for (int ch = tid; ch < 512; ch += 256) {
            const int c = ch >> 3, kk = (ch & 7) * 8;
            uint4 d = *(const uint4*)(Vb + (((size_t)(b * 64 + c)) * Ndim + k0 + kk));
            *(uint4*)(vt + c * 64 + (kk ^ ((c & 7) * 8))) = d;
        }
        if (tid < 64) mt[tid] = (fg[b * Ndim + k0 + tid] != 0) ? 1.f : 0.f;
        __syncthreads();

        // ---- S = Q K^T for 4 key-subtiles of 16 ----
        f32x4 s[4];
#pragma unroll
        for (int st = 0; st < 4; ++st) {
            const int key = st * 16 + li;
            const int row = key * 64;
            const bf16x8 kb0 = *(const bf16x8*)(kt + row + ((8 * g) ^ ((key & 7) * 8)));
            const bf16x8 kb1 = *(const bf16x8*)(kt + row + ((32 + 8 * g) ^ ((key & 7) * 8)));
            f32x4 z = (f32x4){0.f, 0.f, 0.f, 0.f};
            z = __builtin_amdgcn_mfma_f32_16x16x32_bf16(qa0, kb0, z, 0, 0, 0);
            z = __builtin_amdgcn_mfma_f32_16x16x32_bf16(qa1, kb1, z, 0, 0, 0);
            s[st] = z;
        }

        // ---- mask + scale + online softmax ----
        float mk[4];
#pragma unroll
        for (int st = 0; st < 4; ++st) mk[st] = mt[st * 16 + li];
        float tmax[4] = {-1e30f, -1e30f, -1e30f, -1e30f};
#pragma unroll
        for (int st = 0; st < 4; ++st)
#pragma unroll
            for (int r = 0; r < 4; ++r) {
                const float sv = (mk[st] != 0.f) ? s[st][r] * 0.125f : -1e30f;
                s[st][r] = sv;
                tmax[r]  = fmaxf(tmax[r], sv);
            }
#pragma unroll
        for (int r = 0; r < 4; ++r) {
            float v = tmax[r];
            v = fmaxf(v, __shfl_xor(v, 1));
            v = fmaxf(v, __shfl_xor(v, 2));
            v = fmaxf(v, __shfl_xor(v, 4));
            v = fmaxf(v, __shfl_xor(v, 8));
            tmax[r] = v;
        }
        float scale[4], psum[4];
#pragma unroll
        for (int r = 0; r < 4; ++r) {
            const float mnew = fmaxf(mrun[r], tmax[r]);
            scale[r] = __expf(mrun[r] - mnew);
            mrun[r]  = mnew;
            psum[r]  = 0.f;
        }
#pragma unroll
        for (int st = 0; st < 4; ++st)
#pragma unroll
            for (int r = 0; r < 4; ++r) {
                const float p = mk[st] * __expf(s[st][r] - mrun[r]);
                s[st][r] = p;
                psum[r] += p;
            }
#pragma unroll
        for (int r = 0; r < 4; ++r) {
            float v = psum[r];
            v += __shfl_xor(v, 1);
            v += __shfl_xor(v, 2);
            v += __shfl_xor(v, 4);
            v += __shfl_xor(v, 8);
            lrun[r] = lrun[r] * scale[r] + v;
        }
#pragma unroll
        for (int ct = 0; ct < 4; ++ct)
#pragma unroll
            for (int r = 0; r < 4; ++r) accv[ct][r] *= scale[r];

        // ---- P: D-layout -> LDS bounce -> A-frags (per-wave private) ----
#pragma unroll
        for (int st = 0; st < 4; ++st)
#pragma unroll
            for (int r = 0; r < 4; ++r) {
                const int q = 4 * g + r, key = st * 16 + li;
                ptw[q * 64 + (key ^ ((q & 7) * 8))] = (__bf16)s[st][r];
            }
        const bf16x8 pa0 = *(const bf16x8*)(ptw + li * 64 + ((8 * g) ^ ((li & 7) * 8)));
        const bf16x8 pa1 = *(const bf16x8*)(ptw + li * 64 + ((32 + 8 * g) ^ ((li & 7) * 8)));

        // ---- O += P V ----
#pragma unroll
        for (int ct = 0; ct < 4; ++ct) {
            const int c = ct * 16 + li;
            const bf16x8 vb0 = *(const bf16x8*)(vt + c * 64 + ((8 * g) ^ ((c & 7) * 8)));
            const bf16x8 vb1 = *(const bf16x8*)(vt + c * 64 + ((32 + 8 * g) ^ ((c & 7) * 8)));
            accv[ct] = __builtin_amdgcn_mfma_f32_16x16x32_bf16(pa0, vb0, accv[ct], 0, 0, 0);
            accv[ct] = __builtin_amdgcn_mfma_f32_16x16x32_bf16(pa1, vb1, accv[ct], 0, 0, 0);
        }
    }

    // ---- epilogue: normalize, fused out-projection via same LDS bounce ----
    float invl[4];
#pragma unroll
    for (int r = 0; r < 4; ++r) invl[r] = 1.f / lrun[r];
#pragma unroll
    for (int ct = 0; ct < 4; ++ct)
#pragma unroll
        for (int r = 0; r < 4; ++r) {
            accv[ct][r] *= invl[r];
            const int q = 4 * g + r, c = ct * 16 + li;
            ptw[q * 64 + (c ^ ((q & 7) * 8))] = (__bf16)accv[ct][r];
        }
    const bf16x8 oa0 = *(const bf16x8*)(ptw + li * 64 + ((8 * g) ^ ((li & 7) * 8)));
    const bf16x8 oa1 = *(const bf16x8*)(ptw + li * 64 + ((32 + 8 * g) ^ ((li & 7) * 8)));

    const int nbase = qblk * 64 + wv * 16 + 4 * g;
#pragma unroll
    for (int ct = 0; ct < 4; ++ct) {
        const int co = ct * 16 + li;
        // B-frag of w_proj^T: B[ci][co] = w_proj[co][ci], fp32 -> bf16
        const float4 w0a = *(const float4*)(w_proj + co * 64 + 8 * g);
        const float4 w0b = *(const float4*)(w_proj + co * 64 + 8 * g + 4);
        const float4 w1a = *(const float4*)(w_proj + co * 64 + 32 + 8 * g);
        const float4 w1b = *(const float4*)(w_proj + co * 64 + 32 + 8 * g + 4);
        bf16x8 wb0, wb1;
        wb0[0] = (__bf16)w0a.x; wb0[1] = (__bf16)w0a.y; wb0[2] = (__bf16)w0a.z; wb0[3] = (__bf16)w0a.w;
        wb0[4] = (__bf16)w0b.x; wb0[5] = (__bf16)w0b.y; wb0[6] = (__bf16)w0b.z; wb0[7] = (__bf16)w0b.w;
        wb1[0] = (__bf16)w1a.x; wb1[1] = (__bf16)w1a.y; wb1[2] = (__bf16)w1a.z; wb1[3] = (__bf16)w1a.w;
        wb1[4] = (__bf16)w1b.x; wb1[5] = (__bf16)w1b.y; wb1[6] = (__bf16)w1b.z; wb1[7] = (__bf16)w1b.w;
        f32x4 y = (f32x4){0.f, 0.f, 0.f, 0.f};
        y = __builtin_amdgcn_mfma_f32_16x16x32_bf16(oa0, wb0, y, 0, 0, 0);
        y = __builtin_amdgcn_mfma_f32_16x16x32_bf16(oa1, wb1, y, 0, 0, 0);
        const float bp = b_proj[co];
#pragma unroll
        for (int r = 0; r < 4; ++r)
            out[((size_t)(b * 64 + co)) * Ndim + nbase + r] = y[r] + bp;
    }
}

extern "C" void kernel_launch(void* const* d_in, const int* in_sizes, int n_in,
                              void* d_out, int out_size, void* d_ws, size_t ws_size,
                              hipStream_t stream) {
    const float* x      = (const float*)d_in[0];
    const int*   fg     = (const int*)d_in[1];
    const float* w_qkv  = (const float*)d_in[2];
    const float* w_proj = (const float*)d_in[3];
    const float* b_proj = (const float*)d_in[4];
    float* out = (float*)d_out;

    const size_t per = (size_t)Bdim * Cdim * Ndim;  // 2,097,152 elems
    __bf16* Qb = (__bf16*)d_ws;
    __bf16* Kb = Qb + per;
    __bf16* Vb = Kb + per;

    qkv_kernel<<<dim3(Bdim * (Ndim / 64) * 3), dim3(64), 0, stream>>>(
        x, w_qkv, Qb, Kb, Vb);
    attn_kernel<<<dim3(Bdim * (Ndim / 64)), dim3(256), 0, stream>>>(
        Qb, Kb, Vb, fg, w_proj, b_proj, out);
}

// Round 3
// 137.240 us; speedup vs baseline: 33.2235x; 1.5691x over previous
//
#include <hip/hip_runtime.h>
#include <math.h>

#define Bdim 8
#define Cdim 64
#define Ndim 4096
#define NT   (Ndim / 64)

typedef __bf16 bf16x8 __attribute__((ext_vector_type(8)));
typedef float  f32x4  __attribute__((ext_vector_type(4)));

__device__ __forceinline__ void gload_lds16(const void* g, void* l) {
    __builtin_amdgcn_global_load_lds(
        (const __attribute__((address_space(1))) void*)g,
        (__attribute__((address_space(3))) void*)l, 16, 0, 0);
}

__device__ __forceinline__ float fexp2(float x) {
#if __has_builtin(__builtin_amdgcn_exp2f)
    return __builtin_amdgcn_exp2f(x);
#else
    return exp2f(x);
#endif
}

// ---------------------------------------------------------------------------
// Kernel 1: QKV projection (unchanged from round 2).
//   Qb [B][N][C] row-major, Kb [B][N][C] row-major, Vb [B][C][N] chan-major.
// ---------------------------------------------------------------------------
__global__ __launch_bounds__(64) void qkv_kernel(
    const float* __restrict__ x, const float* __restrict__ w_qkv,
    __bf16* __restrict__ Qb, __bf16* __restrict__ Kb, __bf16* __restrict__ Vb)
{
    __shared__ float wsm[64 * 64];
    const int bx  = blockIdx.x;
    const int jc  = bx % 3;
    const int nc  = (bx / 3) % (Ndim / 64);
    const int b   = bx / (3 * (Ndim / 64));
    const int tid = threadIdx.x;
    const int n   = nc * 64 + tid;

    for (int i = tid; i < 64 * 64; i += 64) wsm[i] = w_qkv[jc * 64 * 64 + i];

    float xr[64];
#pragma unroll
    for (int c = 0; c < 64; ++c)
        xr[c] = x[((size_t)(b * 64 + c)) * Ndim + n];
    __syncthreads();

    float acc[64];
    for (int j = 0; j < 64; ++j) {
        float a = 0.f;
#pragma unroll
        for (int c = 0; c < 64; ++c) a += xr[c] * wsm[j * 64 + c];
        acc[j] = a;
    }

    if (jc == 2) {
#pragma unroll
        for (int j = 0; j < 64; ++j)
            Vb[((size_t)(b * 64 + j)) * Ndim + n] = (__bf16)acc[j];
    } else {
        __bf16 row[64];
#pragma unroll
        for (int j = 0; j < 64; ++j) row[j] = (__bf16)acc[j];
        __bf16* dst = ((jc == 0) ? Qb : Kb) + ((size_t)(b * Ndim) + n) * 64;
        const uint4* src = (const uint4*)row;
#pragma unroll
        for (int i = 0; i < 8; ++i) ((uint4*)dst)[i] = src[i];
    }
}

// ---------------------------------------------------------------------------
// Kernel 2: MFMA flash attention, S^T form, async gload_lds pipeline.
// Block = 4 waves (256 thr), 64 q-rows (16/wave). KV tiles of 64 keys,
// double-buffered. S^T = mfma(K, Q): lane(g,li) holds S^T[16st+4g+r][li].
// PV/out-proj use the permuted-k trick: kappa(g,j)=16*(j>>2)+4g+(j&3) so the
// B operand is the lane's own registers (no P redistribution at all).
// LDS XOR swizzle applied on the *global source* (linear gload_lds dest) and
// on the read side (rule #21 both-sides involution).
// ---------------------------------------------------------------------------
__global__ __launch_bounds__(256) void attn_kernel(
    const __bf16* __restrict__ Qb, const __bf16* __restrict__ Kb,
    const __bf16* __restrict__ Vb, const int* __restrict__ fg,
    const float* __restrict__ w_proj, const float* __restrict__ b_proj,
    float* __restrict__ out)
{
    __shared__ __bf16 kt[2][64 * 64];   // [buf][key][c]  (c-granule ^ (key&7))
    __shared__ __bf16 vt[2][64 * 64];   // [buf][c][key]  (key-granule ^ (c&7))
    __shared__ float  mtf[2][64];       // mask bias: 0 or -1e30

    const int bx   = blockIdx.x;
    const int b    = bx >> 6;
    const int qblk = bx & 63;
    const int tid  = threadIdx.x;
    const int wv   = tid >> 6;
    const int l    = tid & 63;
    const int g    = l >> 4;
    const int li   = l & 15;

    // Q B-frags (B[k=c][col=qrow=li]): lane reads Q[qrow][8g..] contiguous.
    const int qrow = qblk * 64 + wv * 16 + li;
    const __bf16* qbase = Qb + (((size_t)b * Ndim + qrow) * 64);
    const bf16x8 qa0 = *(const bf16x8*)(qbase + 8 * g);
    const bf16x8 qa1 = *(const bf16x8*)(qbase + 32 + 8 * g);

    // Staging geometry: wave wv stages rows wv*16 .. wv*16+15 (2 calls of 8).
    // Lane l covers row (base + l>>3), 16B granule (l&7), source pre-swizzled.
    const int srow = wv * 16;
    const int lrow = l >> 3;
    const int lgr  = 8 * ((l & 7) ^ lrow);   // swizzled elem offset in row
    const __bf16* ksrc = Kb + (((size_t)b * Ndim + srow + lrow) * 64) + lgr;
    const __bf16* vsrc = Vb + (((size_t)(b * 64) + srow + lrow) * Ndim) + lgr;

    auto stage = [&](int t, int buf) {
        const size_t ko = (size_t)t * 64 * 64;
        gload_lds16(ksrc + ko,             &kt[buf][srow * 64]);
        gload_lds16(ksrc + ko + 8 * 64,    &kt[buf][(srow + 8) * 64]);
        gload_lds16(vsrc + t * 64,             &vt[buf][srow * 64]);
        gload_lds16(vsrc + t * 64 + 8 * Ndim,  &vt[buf][(srow + 8) * 64]);
        if (tid < 64)
            mtf[buf][tid] = fg[b * Ndim + t * 64 + tid] ? 0.f : -1e30f;
    };

    f32x4 accv[4];
#pragma unroll
    for (int ct = 0; ct < 4; ++ct) accv[ct] = (f32x4){0.f, 0.f, 0.f, 0.f};
    float mrun = -1e30f, lrun = 0.f;

    stage(0, 0);

    const float KS = 0.125f * 1.44269504089f;   // (1/sqrt(C)) * log2(e)

    for (int t = 0; t < NT; ++t) {
        const int buf = t & 1;
        __syncthreads();                  // drains vmcnt -> tile t resident
        if (t + 1 < NT) stage(t + 1, buf ^ 1);

        // mask bias for this lane's 16 keys (16st+4g+r)
        f32x4 mbv[4];
#pragma unroll
        for (int st = 0; st < 4; ++st)
            mbv[st] = *(const f32x4*)(&mtf[buf][16 * st + 4 * g]);

        // ---- S^T = K Q^T ----
        f32x4 s2[4];
#pragma unroll
        for (int st = 0; st < 4; ++st) {
            const int key = 16 * st + li;
            const int sw  = (key & 7) * 8;
            const bf16x8 kb0 = *(const bf16x8*)(&kt[buf][key * 64 + ((8 * g) ^ sw)]);
            const bf16x8 kb1 = *(const bf16x8*)(&kt[buf][key * 64 + ((32 + 8 * g) ^ sw)]);
            f32x4 z = (f32x4){0.f, 0.f, 0.f, 0.f};
            z = __builtin_amdgcn_mfma_f32_16x16x32_bf16(kb0, qa0, z, 0, 0, 0);
            z = __builtin_amdgcn_mfma_f32_16x16x32_bf16(kb1, qa1, z, 0, 0, 0);
            // scale to base-2 domain + additive mask bias
#pragma unroll
            for (int r = 0; r < 4; ++r) s2[st][r] = z[r] * KS + mbv[st][r];
        }

        // ---- online softmax (per-lane row, g-redundant copies) ----
        float tm = -1e30f;
#pragma unroll
        for (int st = 0; st < 4; ++st) {
            const float a = fmaxf(fmaxf(s2[st][0], s2[st][1]),
                                  fmaxf(s2[st][2], s2[st][3]));
            tm = fmaxf(tm, a);
        }
        tm = fmaxf(tm, __shfl_xor(tm, 16));
        tm = fmaxf(tm, __shfl_xor(tm, 32));

        const float mnew = fmaxf(mrun, tm);
        const float sc   = fexp2(mrun - mnew);
        mrun = mnew;

        f32x4 p[4];
        float ps = 0.f;
#pragma unroll
        for (int st = 0; st < 4; ++st)
#pragma unroll
            for (int r = 0; r < 4; ++r) {
                const float e = fexp2(s2[st][r] - mnew);
                p[st][r] = e;
                ps += e;
            }
        ps += __shfl_xor(ps, 16);
        ps += __shfl_xor(ps, 32);
        lrun = lrun * sc + ps;

#pragma unroll
        for (int ct = 0; ct < 4; ++ct)
#pragma unroll
            for (int r = 0; r < 4; ++r) accv[ct][r] *= sc;

        // ---- P B-frags: the lane's own p values (permuted-k, no shuffle) ----
        bf16x8 pb01, pb23;
#pragma unroll
        for (int r = 0; r < 4; ++r) {
            pb01[r]     = (__bf16)p[0][r];
            pb01[4 + r] = (__bf16)p[1][r];
            pb23[r]     = (__bf16)p[2][r];
            pb23[4 + r] = (__bf16)p[3][r];
        }

        // ---- O^T += V^T P^T with matching permuted-k V A-frags ----
#pragma unroll
        for (int ct = 0; ct < 4; ++ct) {
            const int c   = 16 * ct + li;
            const int swc = (c & 7) * 8;
            const __bf16* vrow = &vt[buf][c * 64];
            const uint2 a0 = *(const uint2*)(vrow + ((4 * g) & 7)      + (((4 * g) & ~7) ^ swc));
            const uint2 a1 = *(const uint2*)(vrow + ((16 + 4 * g) & 7) + (((16 + 4 * g) & ~7) ^ swc));
            const uint2 a2 = *(const uint2*)(vrow + ((32 + 4 * g) & 7) + (((32 + 4 * g) & ~7) ^ swc));
            const uint2 a3 = *(const uint2*)(vrow + ((48 + 4 * g) & 7) + (((48 + 4 * g) & ~7) ^ swc));
            uint4 w0; w0.x = a0.x; w0.y = a0.y; w0.z = a1.x; w0.w = a1.y;
            uint4 w1; w1.x = a2.x; w1.y = a2.y; w1.z = a3.x; w1.w = a3.y;
            const bf16x8 vf0 = __builtin_bit_cast(bf16x8, w0);
            const bf16x8 vf1 = __builtin_bit_cast(bf16x8, w1);
            accv[ct] = __builtin_amdgcn_mfma_f32_16x16x32_bf16(vf0, pb01, accv[ct], 0, 0, 0);
            accv[ct] = __builtin_amdgcn_mfma_f32_16x16x32_bf16(vf1, pb23, accv[ct], 0, 0, 0);
        }
    }

    // ---- epilogue: normalize + fused out-projection (same permuted-k) ----
    const float invl = 1.f / lrun;
    bf16x8 ob01, ob23;
#pragma unroll
    for (int r = 0; r < 4; ++r) {
        ob01[r]     = (__bf16)(accv[0][r] * invl);
        ob01[4 + r] = (__bf16)(accv[1][r] * invl);
        ob23[r]     = (__bf16)(accv[2][r] * invl);
        ob23[4 + r] = (__bf16)(accv[3][r] * invl);
    }

    const int nbase = qblk * 64 + wv * 16;
#pragma unroll
    for (int cot = 0; cot < 4; ++cot) {
        const int co = 16 * cot + li;           // A-frag row this lane loads
        const float* wr = w_proj + co * 64;
        const float4 f0 = *(const float4*)(wr + 4 * g);
        const float4 f1 = *(const float4*)(wr + 16 + 4 * g);
        const float4 f2 = *(const float4*)(wr + 32 + 4 * g);
        const float4 f3 = *(const float4*)(wr + 48 + 4 * g);
        bf16x8 wf0, wf1;
        wf0[0] = (__bf16)f0.x; wf0[1] = (__bf16)f0.y; wf0[2] = (__bf16)f0.z; wf0[3] = (__bf16)f0.w;
        wf0[4] = (__bf16)f1.x; wf0[5] = (__bf16)f1.y; wf0[6] = (__bf16)f1.z; wf0[7] = (__bf16)f1.w;
        wf1[0] = (__bf16)f2.x; wf1[1] = (__bf16)f2.y; wf1[2] = (__bf16)f2.z; wf1[3] = (__bf16)f2.w;
        wf1[4] = (__bf16)f3.x; wf1[5] = (__bf16)f3.y; wf1[6] = (__bf16)f3.z; wf1[7] = (__bf16)f3.w;

        f32x4 y = (f32x4){0.f, 0.f, 0.f, 0.f};
        y = __builtin_amdgcn_mfma_f32_16x16x32_bf16(wf0, ob01, y, 0, 0, 0);
        y = __builtin_amdgcn_mfma_f32_16x16x32_bf16(wf1, ob23, y, 0, 0, 0);

        const f32x4 bp = *(const f32x4*)(b_proj + 16 * cot + 4 * g);
#pragma unroll
        for (int r = 0; r < 4; ++r) {
            const int co_s = 16 * cot + 4 * g + r;   // D row mapping
            out[((size_t)(b * 64 + co_s)) * Ndim + nbase + li] = y[r] + bp[r];
        }
    }
}

extern "C" void kernel_launch(void* const* d_in, const int* in_sizes, int n_in,
                              void* d_out, int out_size, void* d_ws, size_t ws_size,
                              hipStream_t stream) {
    const float* x      = (const float*)d_in[0];
    const int*   fg     = (const int*)d_in[1];
    const float* w_qkv  = (const float*)d_in[2];
    const float* w_proj = (const float*)d_in[3];
    const float* b_proj = (const float*)d_in[4];
    float* out = (float*)d_out;

    const size_t per = (size_t)Bdim * Cdim * Ndim;
    __bf16* Qb = (__bf16*)d_ws;
    __bf16* Kb = Qb + per;
    __bf16* Vb = Kb + per;

    qkv_kernel<<<dim3(Bdim * (Ndim / 64) * 3), dim3(64), 0, stream>>>(
        x, w_qkv, Qb, Kb, Vb);
    attn_kernel<<<dim3(Bdim * (Ndim / 64)), dim3(256), 0, stream>>>(
        Qb, Kb, Vb, fg, w_proj, b_proj, out);
}

// Round 4
// 105.435 us; speedup vs baseline: 43.2457x; 1.3017x over previous
//
#include <hip/hip_runtime.h>
#include <math.h>

#define Bdim 8
#define Cdim 64
#define Ndim 4096
#define NT   (Ndim / 64)
#define HT   (NT / 2)          // tiles per key-group

typedef __bf16 bf16x8 __attribute__((ext_vector_type(8)));
typedef float  f32x4  __attribute__((ext_vector_type(4)));

__device__ __forceinline__ void gload_lds16(const void* g, void* l) {
    __builtin_amdgcn_global_load_lds(
        (const __attribute__((address_space(1))) void*)g,
        (__attribute__((address_space(3))) void*)l, 16, 0, 0);
}

__device__ __forceinline__ float fexp2(float x) {
#if __has_builtin(__builtin_amdgcn_exp2f)
    return __builtin_amdgcn_exp2f(x);
#else
    return exp2f(x);
#endif
}

// ---------------------------------------------------------------------------
// Kernel 1: QKV projection (unchanged).
//   Qb [B][N][C] row-major, Kb [B][N][C] row-major, Vb [B][C][N] chan-major.
// ---------------------------------------------------------------------------
__global__ __launch_bounds__(64) void qkv_kernel(
    const float* __restrict__ x, const float* __restrict__ w_qkv,
    __bf16* __restrict__ Qb, __bf16* __restrict__ Kb, __bf16* __restrict__ Vb)
{
    __shared__ float wsm[64 * 64];
    const int bx  = blockIdx.x;
    const int jc  = bx % 3;
    const int nc  = (bx / 3) % (Ndim / 64);
    const int b   = bx / (3 * (Ndim / 64));
    const int tid = threadIdx.x;
    const int n   = nc * 64 + tid;

    for (int i = tid; i < 64 * 64; i += 64) wsm[i] = w_qkv[jc * 64 * 64 + i];

    float xr[64];
#pragma unroll
    for (int c = 0; c < 64; ++c)
        xr[c] = x[((size_t)(b * 64 + c)) * Ndim + n];
    __syncthreads();

    float acc[64];
    for (int j = 0; j < 64; ++j) {
        float a = 0.f;
#pragma unroll
        for (int c = 0; c < 64; ++c) a += xr[c] * wsm[j * 64 + c];
        acc[j] = a;
    }

    if (jc == 2) {
#pragma unroll
        for (int j = 0; j < 64; ++j)
            Vb[((size_t)(b * 64 + j)) * Ndim + n] = (__bf16)acc[j];
    } else {
        __bf16 row[64];
#pragma unroll
        for (int j = 0; j < 64; ++j) row[j] = (__bf16)acc[j];
        __bf16* dst = ((jc == 0) ? Qb : Kb) + ((size_t)(b * Ndim) + n) * 64;
        const uint4* src = (const uint4*)row;
#pragma unroll
        for (int i = 0; i < 8; ++i) ((uint4*)dst)[i] = src[i];
    }
}

// ---------------------------------------------------------------------------
// Kernel 2: MFMA flash attention, split-key 8-wave blocks, pi-permuted K.
//   waves 0-3: key tiles 0..HT-1;  waves 4-7: key tiles HT..NT-1.
//   kt row R holds key pi(R) = 8g+32(st>>1)+4(st&1)+r for R=16st+4g+r, so the
//   lane's own p registers ARE the standard B-frag and V reads are b128.
//   End-of-kernel online-softmax merge through LDS (overlaid on kt).
// ---------------------------------------------------------------------------
__global__ __launch_bounds__(512, 4) void attn_kernel(
    const __bf16* __restrict__ Qb, const __bf16* __restrict__ Kb,
    const __bf16* __restrict__ Vb, const int* __restrict__ fg,
    const float* __restrict__ w_proj, const float* __restrict__ b_proj,
    float* __restrict__ out)
{
    __shared__ __align__(16) __bf16 kt[2][2][64 * 64];  // [grp][buf][R][c]
    __shared__ __align__(16) __bf16 vt[2][2][64 * 64];  // [grp][buf][c][key]
    __shared__ float mtf[2][2][64];                     // mask bias by key

    const int bx   = blockIdx.x;
    const int b    = bx >> 6;
    const int qblk = bx & 63;
    const int tid  = threadIdx.x;
    const int wv   = tid >> 6;
    const int grp  = wv >> 2;
    const int wsub = wv & 3;
    const int l    = tid & 63;
    const int g    = l >> 4;
    const int li   = l & 15;

    // Q B-frags: B[k=c][col=qrow]; lane reads Q[qrow][8g..] contiguous.
    const int qrow = qblk * 64 + wsub * 16 + li;
    const __bf16* qbase = Qb + (((size_t)b * Ndim + qrow) * 64);
    const bf16x8 qa0 = *(const bf16x8*)(qbase + 8 * g);
    const bf16x8 qa1 = *(const bf16x8*)(qbase + 32 + 8 * g);

    // Staging: wave stages LDS rows srow..srow+15 (2 gload calls of 8 rows).
    const int srow = wsub * 16;
    const int lrow = l >> 3;
    const int lgr  = 8 * ((l & 7) ^ lrow);   // 16B-granule XOR swizzle (src side)
    // pi for K rows: R = srow + lrow (wsub fields: st-bits from wsub)
    const int pi0 = 8 * (lrow >> 2) + 32 * (wsub >> 1) + 4 * (wsub & 1) + (lrow & 3);
    const __bf16* ksrc0 = Kb + (((size_t)b * Ndim + pi0) * 64) + lgr;       // pi1 = pi0+16
    const __bf16* vsrc0 = Vb + (((size_t)(b * 64) + srow + lrow) * Ndim) + lgr;

    const int t0 = grp * HT;

    auto stage = [&](int t, int buf) {
        const size_t ko = (size_t)t * 4096;
        gload_lds16(ksrc0 + ko,             &kt[grp][buf][srow * 64]);
        gload_lds16(ksrc0 + ko + 16 * 64,   &kt[grp][buf][(srow + 8) * 64]);
        gload_lds16(vsrc0 + t * 64,             &vt[grp][buf][srow * 64]);
        gload_lds16(vsrc0 + t * 64 + 8 * Ndim,  &vt[grp][buf][(srow + 8) * 64]);
        if (wsub == 0)
            mtf[grp][buf][l] = fg[b * Ndim + t * 64 + l] ? 0.f : -1e30f;
    };

    f32x4 accv[4];
#pragma unroll
    for (int ct = 0; ct < 4; ++ct) accv[ct] = (f32x4){0.f, 0.f, 0.f, 0.f};
    float mrun = -1e30f, lrun = 0.f;

    stage(t0, 0);

    const float KS = 0.125f * 1.44269504089f;   // (1/sqrt(C)) * log2(e)

    for (int it = 0; it < HT; ++it) {
        const int buf = it & 1;
        __syncthreads();                  // tile t0+it resident
        if (it + 1 < HT) stage(t0 + it + 1, buf ^ 1);

        // mask bias: key(st,r) = 8g + 32*(st>>1) + 4*(st&1) + r
        f32x4 mb[4];
        mb[0] = *(const f32x4*)(&mtf[grp][buf][8 * g]);
        mb[1] = *(const f32x4*)(&mtf[grp][buf][8 * g + 4]);
        mb[2] = *(const f32x4*)(&mtf[grp][buf][8 * g + 32]);
        mb[3] = *(const f32x4*)(&mtf[grp][buf][8 * g + 36]);

        // ---- S^T = K Q^T (rows are pi-permuted keys) ----
        f32x4 s2[4];
#pragma unroll
        for (int st = 0; st < 4; ++st) {
            const int R  = 16 * st + li;
            const int sw = (li & 7) * 8;
            const bf16x8 kb0 = *(const bf16x8*)(&kt[grp][buf][R * 64 + ((8 * g) ^ sw)]);
            const bf16x8 kb1 = *(const bf16x8*)(&kt[grp][buf][R * 64 + ((32 + 8 * g) ^ sw)]);
            f32x4 z = (f32x4){0.f, 0.f, 0.f, 0.f};
            z = __builtin_amdgcn_mfma_f32_16x16x32_bf16(kb0, qa0, z, 0, 0, 0);
            z = __builtin_amdgcn_mfma_f32_16x16x32_bf16(kb1, qa1, z, 0, 0, 0);
#pragma unroll
            for (int r = 0; r < 4; ++r) s2[st][r] = z[r] * KS + mb[st][r];
        }

        // ---- online softmax (per-lane q-column) ----
        float tm = -1e30f;
#pragma unroll
        for (int st = 0; st < 4; ++st) {
            const float a = fmaxf(fmaxf(s2[st][0], s2[st][1]),
                                  fmaxf(s2[st][2], s2[st][3]));
            tm = fmaxf(tm, a);
        }
        tm = fmaxf(tm, __shfl_xor(tm, 16));
        tm = fmaxf(tm, __shfl_xor(tm, 32));

        const float mnew = fmaxf(mrun, tm);
        const float sc   = fexp2(mrun - mnew);
        mrun = mnew;

        f32x4 p[4];
        float ps = 0.f;
#pragma unroll
        for (int st = 0; st < 4; ++st)
#pragma unroll
            for (int r = 0; r < 4; ++r) {
                const float e = fexp2(s2[st][r] - mnew);
                p[st][r] = e;
                ps += e;
            }
        ps += __shfl_xor(ps, 16);
        ps += __shfl_xor(ps, 32);
        lrun = lrun * sc + ps;

#pragma unroll
        for (int ct = 0; ct < 4; ++ct)
#pragma unroll
            for (int r = 0; r < 4; ++r) accv[ct][r] *= sc;

        // ---- P B-frags = the lane's own registers (standard layout now) ----
        bf16x8 pb01, pb23;
#pragma unroll
        for (int r = 0; r < 4; ++r) {
            pb01[r]     = (__bf16)p[0][r];
            pb01[4 + r] = (__bf16)p[1][r];
            pb23[r]     = (__bf16)p[2][r];
            pb23[4 + r] = (__bf16)p[3][r];
        }

        // ---- O^T += V^T P^T : V A-frags are contiguous b128 reads ----
#pragma unroll
        for (int ct = 0; ct < 4; ++ct) {
            const int c = 16 * ct + li;
            const bf16x8 vf0 = *(const bf16x8*)(&vt[grp][buf][c * 64 + 8 * (g ^ (c & 7))]);
            const bf16x8 vf1 = *(const bf16x8*)(&vt[grp][buf][c * 64 + 8 * ((4 + g) ^ (c & 7))]);
            accv[ct] = __builtin_amdgcn_mfma_f32_16x16x32_bf16(vf0, pb01, accv[ct], 0, 0, 0);
            accv[ct] = __builtin_amdgcn_mfma_f32_16x16x32_bf16(vf1, pb23, accv[ct], 0, 0, 0);
        }
    }

    // ---- merge group 1 into group 0 via LDS overlay on kt ----
    float* mrg = (float*)&kt[0][0][0];   // 18 KB used, 32 KB available
    __syncthreads();                     // all tile reads done
    if (grp == 1) {
        if (g == 0) {
            mrg[wsub * 128 + li * 2 + 0] = mrun;
            mrg[wsub * 128 + li * 2 + 1] = lrun;
        }
        float* o1 = mrg + 512 + ((size_t)(wsub * 64 + l)) * 16;
#pragma unroll
        for (int ct = 0; ct < 4; ++ct)
            *(f32x4*)(o1 + 4 * ct) = accv[ct];
    }
    __syncthreads();
    if (grp == 1) return;

    const float m1 = mrg[wsub * 128 + li * 2 + 0];
    const float l1 = mrg[wsub * 128 + li * 2 + 1];
    const float m  = fmaxf(mrun, m1);
    const float a0 = fexp2(mrun - m);
    const float a1 = fexp2(m1 - m);
    const float inv = 1.f / (lrun * a0 + l1 * a1);
    const float* o1 = mrg + 512 + ((size_t)(wsub * 64 + l)) * 16;

    bf16x8 ob01, ob23;
#pragma unroll
    for (int r = 0; r < 4; ++r) {
        ob01[r]     = (__bf16)((accv[0][r] * a0 + o1[0 + r]  * a1) * inv);
        ob01[4 + r] = (__bf16)((accv[1][r] * a0 + o1[4 + r]  * a1) * inv);
        ob23[r]     = (__bf16)((accv[2][r] * a0 + o1[8 + r]  * a1) * inv);
        ob23[4 + r] = (__bf16)((accv[3][r] * a0 + o1[12 + r] * a1) * inv);
    }

    // ---- fused out-projection (permuted-k against ob packing) ----
    const int nbase = qblk * 64 + wsub * 16;
#pragma unroll
    for (int cot = 0; cot < 4; ++cot) {
        const int co = 16 * cot + li;
        const float* wr = w_proj + co * 64;
        const float4 f0 = *(const float4*)(wr + 4 * g);
        const float4 f1 = *(const float4*)(wr + 16 + 4 * g);
        const float4 f2 = *(const float4*)(wr + 32 + 4 * g);
        const float4 f3 = *(const float4*)(wr + 48 + 4 * g);
        bf16x8 wf0, wf1;
        wf0[0] = (__bf16)f0.x; wf0[1] = (__bf16)f0.y; wf0[2] = (__bf16)f0.z; wf0[3] = (__bf16)f0.w;
        wf0[4] = (__bf16)f1.x; wf0[5] = (__bf16)f1.y; wf0[6] = (__bf16)f1.z; wf0[7] = (__bf16)f1.w;
        wf1[0] = (__bf16)f2.x; wf1[1] = (__bf16)f2.y; wf1[2] = (__bf16)f2.z; wf1[3] = (__bf16)f2.w;
        wf1[4] = (__bf16)f3.x; wf1[5] = (__bf16)f3.y; wf1[6] = (__bf16)f3.z; wf1[7] = (__bf16)f3.w;

        f32x4 y = (f32x4){0.f, 0.f, 0.f, 0.f};
        y = __builtin_amdgcn_mfma_f32_16x16x32_bf16(wf0, ob01, y, 0, 0, 0);
        y = __builtin_amdgcn_mfma_f32_16x16x32_bf16(wf1, ob23, y, 0, 0, 0);

        const f32x4 bp = *(const f32x4*)(b_proj + 16 * cot + 4 * g);
#pragma unroll
        for (int r = 0; r < 4; ++r) {
            const int co_s = 16 * cot + 4 * g + r;
            out[((size_t)(b * 64 + co_s)) * Ndim + nbase + li] = y[r] + bp[r];
        }
    }
}

extern "C" void kernel_launch(void* const* d_in, const int* in_sizes, int n_in,
                              void* d_out, int out_size, void* d_ws, size_t ws_size,
                              hipStream_t stream) {
    const float* x      = (const float*)d_in[0];
    const int*   fg     = (const int*)d_in[1];
    const float* w_qkv  = (const float*)d_in[2];
    const float* w_proj = (const float*)d_in[3];
    const float* b_proj = (const float*)d_in[4];
    float* out = (float*)d_out;

    const size_t per = (size_t)Bdim * Cdim * Ndim;
    __bf16* Qb = (__bf16*)d_ws;
    __bf16* Kb = Qb + per;
    __bf16* Vb = Kb + per;

    qkv_kernel<<<dim3(Bdim * (Ndim / 64) * 3), dim3(64), 0, stream>>>(
        x, w_qkv, Qb, Kb, Vb);
    attn_kernel<<<dim3(Bdim * (Ndim / 64)), dim3(512), 0, stream>>>(
        Qb, Kb, Vb, fg, w_proj, b_proj, out);
}